// Round 1
// 134.954 us; speedup vs baseline: 1.0271x; 1.0271x over previous
//
#include <hip/hip_runtime.h>

#define HH 80
#define WW 80
#define NPIX 6400          // 80*80
#define NB 4
#define BN 25600           // NB * NPIX
#define CDIM 256
#define QKVC 768
#define SCALE 0.17677669529663689f   // 32^-0.5

typedef __attribute__((ext_vector_type(8))) short short8;
typedef __attribute__((ext_vector_type(4))) float floatx4;

__device__ __forceinline__ float b2f(ushort u) {
    return __uint_as_float(((uint)u) << 16);
}
__device__ __forceinline__ ushort f2b(float f) {
    uint u = __float_as_uint(f);
    return (ushort)((u + 0x7fffu + ((u >> 16) & 1u)) >> 16);   // RNE
}
__device__ __forceinline__ void unpack8(uint4 v, float* f) {
    f[0] = __uint_as_float(v.x << 16); f[1] = __uint_as_float(v.x & 0xffff0000u);
    f[2] = __uint_as_float(v.y << 16); f[3] = __uint_as_float(v.y & 0xffff0000u);
    f[4] = __uint_as_float(v.z << 16); f[5] = __uint_as_float(v.z & 0xffff0000u);
    f[6] = __uint_as_float(v.w << 16); f[7] = __uint_as_float(v.w & 0xffff0000u);
}
__device__ __forceinline__ void gload_lds16(const void* gptr, void* lptr) {
    __builtin_amdgcn_global_load_lds(
        (const __attribute__((address_space(1))) unsigned int*)gptr,
        (__attribute__((address_space(3))) unsigned int*)lptr,
        16, 0, 0);
}

// ---------------------------------------------------------------------------
// Fused cast kernel.
//  blocks x <  100: Yb[n][c] = bf16(concat(rgb, ir)) via LDS transpose tile
//  blocks x >= 100: cast w_qkv / w_proj to bf16 (flat)
// ---------------------------------------------------------------------------
__global__ __launch_bounds__(256) void cast_all_k(
    const float* __restrict__ rgb, const float* __restrict__ ir,
    const float* __restrict__ wq, const float* __restrict__ wp,
    ushort* __restrict__ Yb, ushort* __restrict__ wqb, ushort* __restrict__ wpb)
{
    const int tid = threadIdx.x;
    if (blockIdx.x >= 100) {
        int i = (((blockIdx.x - 100) * 8 + blockIdx.y) * 4 + blockIdx.z) * 256 + tid;
        if (i < QKVC * CDIM) wqb[i] = f2b(wq[i]);
        else                 wpb[i - QKVC * CDIM] = f2b(wp[i - QKVC * CDIM]);
        return;
    }
    __shared__ ushort T[32][72];
    const int pix0 = blockIdx.x * 64;
    const int cb = blockIdx.y;
    const int b = blockIdx.z;

    const int pl = tid & 63, cg = tid >> 6;
    #pragma unroll
    for (int cc = 0; cc < 32; cc += 4) {
        int c = cb * 32 + cc + cg;
        const float* src = (c < 128) ? (rgb + ((size_t)b * 128 + c) * NPIX)
                                     : (ir + ((size_t)b * 128 + (c - 128)) * NPIX);
        T[cc + cg][pl] = f2b(src[pix0 + pl]);
    }
    __syncthreads();
    const int nl = tid >> 2, c0 = (tid & 3) * 8;
    ushort tmp[8];
    #pragma unroll
    for (int j = 0; j < 8; ++j) tmp[j] = T[c0 + j][nl];
    uint4 v;
    v.x = tmp[0] | ((uint)tmp[1] << 16);
    v.y = tmp[2] | ((uint)tmp[3] << 16);
    v.z = tmp[4] | ((uint)tmp[5] << 16);
    v.w = tmp[6] | ((uint)tmp[7] << 16);
    *(uint4*)(&Yb[((size_t)(b * NPIX + pix0 + nl)) * CDIM + cb * 32 + c0]) = v;
}

// ---------------------------------------------------------------------------
// BK=64 MFMA NT GEMM body. 128x128 tile, 4 K-iters. Unpadded LDS [m][64] with
// parity-XOR swizzle: odd rows store their two 32-elem k-halves swapped
// (scol = k ^ ((row&1)<<5)), applied on the GLOBAL address so the
// global_load_lds DMA stays flat+contiguous (m104). Frag reads spread across
// all 32 banks -> conflict-free.
// MFMA operands swapped (o = A operand): acc reg r = o offset, lane&15 = n.
// ---------------------------------------------------------------------------
__device__ __forceinline__ void gemm_nt_body64(
    const ushort* __restrict__ A, const ushort* __restrict__ W,
    ushort* As, ushort* Bs, int n0, int o0, floatx4 acc[4][4])
{
    const int tid = threadIdx.x;
    const int lane = tid & 63;
    const int wave = tid >> 6;
    const int wr = wave >> 1, wc = wave & 1;
    const int l15 = lane & 15, quad = lane >> 4;

    const int srow8 = tid >> 3;                        // row within 32-row round
    const int scol  = ((tid & 7) * 8) ^ ((srow8 & 1) << 5);
    const int par   = l15 & 1;                         // frag-row parity

    for (int k0 = 0; k0 < CDIM; k0 += 64) {
        #pragma unroll
        for (int r = 0; r < 4; ++r) {
            const int row = r * 32 + srow8;
            gload_lds16(&A[(size_t)(n0 + row) * CDIM + k0 + scol],
                        As + r * 2048 + wave * 512);
            gload_lds16(&W[(size_t)(o0 + row) * CDIM + k0 + scol],
                        Bs + r * 2048 + wave * 512);
        }
        __syncthreads();
        #pragma unroll
        for (int s = 0; s < 2; ++s) {
            const int fc = ((s ^ par) << 5) + quad * 8;
            short8 af[4], bfr[4];
            #pragma unroll
            for (int i = 0; i < 4; ++i)
                af[i] = *(const short8*)(&As[(wr * 64 + i * 16 + l15) * 64 + fc]);
            #pragma unroll
            for (int j = 0; j < 4; ++j)
                bfr[j] = *(const short8*)(&Bs[(wc * 64 + j * 16 + l15) * 64 + fc]);
            #pragma unroll
            for (int i = 0; i < 4; ++i)
                #pragma unroll
                for (int j = 0; j < 4; ++j)
                    acc[i][j] = __builtin_amdgcn_mfma_f32_16x16x32_bf16(
                        bfr[j], af[i], acc[i][j], 0, 0, 0);   // swapped: rows=o
        }
        __syncthreads();
    }
}

// ---------------------------------------------------------------------------
// QKV GEMM. Output chunk-major qkv2[chunk][n][32], chunk = o>>5
// (chunk 0..7 = Q(dil,head), 8..15 = K, 16..23 = V). 8B packed stores.
// XCD-chunked dispatch: 1200 blocks, bid%8 selects XCD (round-robin HW map);
// within an XCD's 150 consecutive slots, o iterates fastest so the 6 o-blocks
// sharing one A-tile (64 KB of Yb) run back-to-back on the same XCD -> 5/6
// A reads become L2 hits; all of W (384 KB) stays L2-resident per XCD.
// ---------------------------------------------------------------------------
__global__ __launch_bounds__(256) void gemm_qkv_mfma(
    const ushort* __restrict__ Yb, const ushort* __restrict__ Wb,
    ushort* __restrict__ qkv2)
{
    __shared__ __align__(16) ushort As[128 * 64];
    __shared__ __align__(16) ushort Bs[128 * 64];
    const int tid = threadIdx.x;
    const int lane = tid & 63;
    const int wave = tid >> 6;
    const int wr = wave >> 1, wc = wave & 1;
    const int l15 = lane & 15, quad = lane >> 4;

    const int bid = blockIdx.x;                  // grid = 1200 linear
    const int swz = (bid & 7) * 150 + (bid >> 3);
    const int n0 = (swz / 6) * 128;
    const int o0 = (swz % 6) * 128;

    floatx4 acc[4][4] = {};
    gemm_nt_body64(Yb, Wb, As, Bs, n0, o0, acc);

    #pragma unroll
    for (int i = 0; i < 4; ++i) {
        const int n = n0 + wr * 64 + i * 16 + l15;
        #pragma unroll
        for (int j = 0; j < 4; ++j) {
            const int o4 = o0 + wc * 64 + j * 16 + quad * 4;   // 4 consecutive o
            uint2 v;
            v.x = f2b(acc[i][j][0]) | ((uint)f2b(acc[i][j][1]) << 16);
            v.y = f2b(acc[i][j][2]) | ((uint)f2b(acc[i][j][3]) << 16);
            *(uint2*)(qkv2 + (size_t)(o4 >> 5) * BN * 32 + (size_t)n * 32 + (o4 & 31)) = v;
        }
    }
}

// ---------------------------------------------------------------------------
// Tiled dilated local attention, two-phase K/V staging through ONE 31 KB LDS
// buffer. One block = (b, dil, head) x 16x16 pixel tile.
// EDGE=false (interior tiles, 9/25): no clamps/masks. V DMA issued before
// softmax math to overlap. OOB (EDGE): score 0 in softmax denom, value 0.
// ---------------------------------------------------------------------------
template<int D, bool EDGE>
__device__ __forceinline__ void attn_tile(
    const ushort* __restrict__ qkv2, ushort* __restrict__ X2,
    ushort* kl, int b, int dh, int y0, int x0)
{
    constexpr int RW = 16 + 2 * D;
    constexpr int RP = RW * RW;
    const int tid = threadIdx.x;
    const int lane = tid & 63;
    const int wave = tid >> 6;          // = channel chunk c (0..3) for staging
    const ushort* Qc = qkv2 + (size_t)dh * BN * 32;
    const ushort* Kc = qkv2 + (size_t)(8 + dh) * BN * 32;
    const ushort* Vc = qkv2 + (size_t)(16 + dh) * BN * 32;

    const int px = tid & 15, py = tid >> 4;
    const int n = b * NPIX + (y0 + py) * WW + (x0 + px);
    float q[32];
    {
        const uint4* qp = (const uint4*)(Qc + (size_t)n * 32);
        uint4 v0 = qp[0], v1 = qp[1], v2 = qp[2], v3 = qp[3];
        unpack8(v0, q); unpack8(v1, q + 8); unpack8(v2, q + 16); unpack8(v3, q + 24);
    }

    // phase 1: stage K region (wave w = channel chunk w; LDS [c][p][16B])
    #pragma unroll 2
    for (int p0 = 0; p0 < RP; p0 += 64) {
        int p = p0 + lane;
        int ry = p / RW, rx = p % RW;
        int gy = y0 - D + ry, gx = x0 - D + rx;
        if (EDGE) { gy = min(max(gy, 0), HH - 1); gx = min(max(gx, 0), WW - 1); }
        if (p < RP)
            gload_lds16(Kc + (size_t)(b * NPIX + gy * WW + gx) * 32 + wave * 8,
                        kl + (size_t)(wave * RP + p0) * 8);
    }
    __syncthreads();

    float sc[9];
    #pragma unroll
    for (int t = 0; t < 9; ++t) {
        const int dy = t / 3 - 1, dx = t % 3 - 1;
        const int p = (py + D + dy * D) * RW + (px + D + dx * D);
        float s = 0.f;
        bool ok = true;
        if (EDGE) {
            const int yy = y0 + py + dy * D, xx = x0 + px + dx * D;
            ok = (yy >= 0 && yy < HH && xx >= 0 && xx < WW);
        }
        if (ok) {
            #pragma unroll
            for (int c = 0; c < 4; ++c) {
                float kv[8];
                unpack8(*(const uint4*)(kl + (size_t)(c * RP + p) * 8), kv);
                #pragma unroll
                for (int j = 0; j < 8; ++j) s += q[c * 8 + j] * kv[j];
            }
        }
        sc[t] = s * SCALE;              // OOB stays exactly 0 (in softmax denom)
    }
    __syncthreads();                    // all waves done reading K

    // phase 2: issue V DMA first, then softmax math (overlap)
    #pragma unroll 2
    for (int p0 = 0; p0 < RP; p0 += 64) {
        int p = p0 + lane;
        int ry = p / RW, rx = p % RW;
        int gy = y0 - D + ry, gx = x0 - D + rx;
        if (EDGE) { gy = min(max(gy, 0), HH - 1); gx = min(max(gx, 0), WW - 1); }
        if (p < RP)
            gload_lds16(Vc + (size_t)(b * NPIX + gy * WW + gx) * 32 + wave * 8,
                        kl + (size_t)(wave * RP + p0) * 8);
    }

    float m = sc[0];
    #pragma unroll
    for (int t = 1; t < 9; ++t) m = fmaxf(m, sc[t]);
    float sum = 0.f;
    #pragma unroll
    for (int t = 0; t < 9; ++t) { sc[t] = __expf(sc[t] - m); sum += sc[t]; }
    const float inv = 1.f / sum;
    __syncthreads();                    // V DMA landed (vmcnt drained at barrier)

    float o[32];
    #pragma unroll
    for (int hd = 0; hd < 32; ++hd) o[hd] = 0.f;
    #pragma unroll
    for (int t = 0; t < 9; ++t) {
        const int dy = t / 3 - 1, dx = t % 3 - 1;
        const int p = (py + D + dy * D) * RW + (px + D + dx * D);
        bool ok = true;
        if (EDGE) {
            const int yy = y0 + py + dy * D, xx = x0 + px + dx * D;
            ok = (yy >= 0 && yy < HH && xx >= 0 && xx < WW);
        }
        if (ok) {
            const float wgt = sc[t] * inv;
            #pragma unroll
            for (int c = 0; c < 4; ++c) {
                float vv[8];
                unpack8(*(const uint4*)(kl + (size_t)(c * RP + p) * 8), vv);
                #pragma unroll
                for (int j = 0; j < 8; ++j) o[c * 8 + j] += wgt * vv[j];
            }
        }
    }
    uint4* xp = (uint4*)(X2 + (size_t)dh * BN * 32 + (size_t)n * 32);
    #pragma unroll
    for (int m4 = 0; m4 < 4; ++m4) {
        uint4 v;
        v.x = f2b(o[8 * m4 + 0]) | ((uint)f2b(o[8 * m4 + 1]) << 16);
        v.y = f2b(o[8 * m4 + 2]) | ((uint)f2b(o[8 * m4 + 3]) << 16);
        v.z = f2b(o[8 * m4 + 4]) | ((uint)f2b(o[8 * m4 + 5]) << 16);
        v.w = f2b(o[8 * m4 + 6]) | ((uint)f2b(o[8 * m4 + 7]) << 16);
        xp[m4] = v;
    }
}

__global__ __launch_bounds__(256) void attn2_k(
    const ushort* __restrict__ qkv2, ushort* __restrict__ X2)
{
    __shared__ __align__(16) ushort kl[4 * 484 * 8];   // 31 KB (worst case d=3)
    const int tile = blockIdx.x;                       // 0..24
    const int y0 = (tile / 5) * 16, x0 = (tile % 5) * 16;
    const int dh = blockIdx.y;                         // dil*4 + head
    const int b = blockIdx.z;
    const bool inter = (y0 >= 16 && y0 <= 48 && x0 >= 16 && x0 <= 48);
    if (dh < 4) {
        if (inter) attn_tile<2, false>(qkv2, X2, kl, b, dh, y0, x0);
        else       attn_tile<2, true >(qkv2, X2, kl, b, dh, y0, x0);
    } else {
        if (inter) attn_tile<3, false>(qkv2, X2, kl, b, dh, y0, x0);
        else       attn_tile<3, true >(qkv2, X2, kl, b, dh, y0, x0);
    }
}

// ---------------------------------------------------------------------------
// Proj GEMM + epilogue: out[n][co] = X·Wp^T + bias + Y residual.
// Retiled 64n x 128o (was 128x128): 800 blocks (~3/CU co-resident, vs 400 ->
// 1.56/CU where per-iter DMA-drain latency was fully exposed and half the
// CUs idled in round 2). LDS 24 KB. 4 waves in 2x2 grid, each 32n x 64o,
// acc[2][4]. A staged from chunk-major X2: the XOR swizzle's bit-5 flip
// selects between the two 32-wide chunks spanned by BK=64 (chunk_sel).
// XCD-chunked dispatch like qkv (o fastest: A-tile L2-reuse across 2 o-blocks;
// W 128 KB L2-resident).
// ---------------------------------------------------------------------------
__global__ __launch_bounds__(256) void proj_mfma(
    const ushort* __restrict__ X2, const ushort* __restrict__ Wpb,
    const float* __restrict__ bp, const ushort* __restrict__ Yb,
    float* __restrict__ out)
{
    __shared__ __align__(16) ushort As[64 * 64];       //  8 KB
    __shared__ __align__(16) ushort Bs[128 * 64];      // 16 KB
    const int tid = threadIdx.x;
    const int lane = tid & 63;
    const int wave = tid >> 6;
    const int wr = wave >> 1, wc = wave & 1;
    const int l15 = lane & 15, quad = lane >> 4;

    const int bid = blockIdx.x;                  // grid = 800 linear
    const int swz = (bid & 7) * 100 + (bid >> 3);
    const int n0 = (swz >> 1) * 64;
    const int o0 = (swz & 1) * 128;

    const int srow8 = tid >> 3;
    const int scol  = ((tid & 7) * 8) ^ ((srow8 & 1) << 5);
    const int chunk_sel = ((tid >> 2) & 1) ^ (srow8 & 1);
    const int coff  = (tid & 3) * 8;
    const int par   = l15 & 1;

    floatx4 acc[2][4] = {};

    for (int k0 = 0; k0 < CDIM; k0 += 64) {
        const int cbase = k0 >> 5;
        const ushort* Achunk = X2 + (size_t)(cbase + chunk_sel) * BN * 32;
        #pragma unroll
        for (int r = 0; r < 2; ++r) {
            const int row = r * 32 + srow8;
            gload_lds16(&Achunk[(size_t)(n0 + row) * 32 + coff],
                        As + r * 2048 + wave * 512);
        }
        #pragma unroll
        for (int r = 0; r < 4; ++r) {
            const int row = r * 32 + srow8;
            gload_lds16(&Wpb[(size_t)(o0 + row) * CDIM + k0 + scol],
                        Bs + r * 2048 + wave * 512);
        }
        __syncthreads();
        #pragma unroll
        for (int s = 0; s < 2; ++s) {
            const int fc = ((s ^ par) << 5) + quad * 8;
            short8 af[2], bfr[4];
            #pragma unroll
            for (int i = 0; i < 2; ++i)
                af[i] = *(const short8*)(&As[(wr * 32 + i * 16 + l15) * 64 + fc]);
            #pragma unroll
            for (int j = 0; j < 4; ++j)
                bfr[j] = *(const short8*)(&Bs[(wc * 64 + j * 16 + l15) * 64 + fc]);
            #pragma unroll
            for (int i = 0; i < 2; ++i)
                #pragma unroll
                for (int j = 0; j < 4; ++j)
                    acc[i][j] = __builtin_amdgcn_mfma_f32_16x16x32_bf16(
                        bfr[j], af[i], acc[i][j], 0, 0, 0);   // swapped: rows=o
        }
        __syncthreads();
    }

    #pragma unroll
    for (int i = 0; i < 2; ++i) {
        const int n = n0 + wr * 32 + i * 16 + l15;
        #pragma unroll
        for (int j = 0; j < 4; ++j) {
            const int o4 = o0 + wc * 64 + j * 16 + quad * 4;   // 4 consecutive co
            const float4 bias = *(const float4*)(bp + o4);
            const ushort4 res = *(const ushort4*)(Yb + (size_t)n * CDIM + o4);
            float4 v;
            v.x = acc[i][j][0] + bias.x + b2f(res.x);
            v.y = acc[i][j][1] + bias.y + b2f(res.y);
            v.z = acc[i][j][2] + bias.z + b2f(res.z);
            v.w = acc[i][j][3] + bias.w + b2f(res.w);
            *(float4*)(out + (size_t)n * CDIM + o4) = v;
        }
    }
}

extern "C" void kernel_launch(void* const* d_in, const int* in_sizes, int n_in,
                              void* d_out, int out_size, void* d_ws, size_t ws_size,
                              hipStream_t stream) {
    const float* rgb    = (const float*)d_in[0];
    const float* ir     = (const float*)d_in[1];
    const float* w_qkv  = (const float*)d_in[2];
    const float* w_proj = (const float*)d_in[3];
    const float* b_proj = (const float*)d_in[4];
    float* out = (float*)d_out;

    ushort* qkv2 = (ushort*)d_ws;                    // 24 chunks * 25600*32 = 39.3 MB
    ushort* Yb   = qkv2 + (size_t)24 * BN * 32;      // 25600*256 = 13.1 MB
    ushort* X2   = Yb + (size_t)BN * CDIM;           // 8 chunks * 25600*32 = 13.1 MB
    ushort* Wqb  = X2 + (size_t)8 * BN * 32;         // 768*256
    ushort* Wpb  = Wqb + (size_t)QKVC * CDIM;        // 256*256

    cast_all_k<<<dim3(132, 8, NB), 256, 0, stream>>>(rgb, ir, w_qkv, w_proj,
                                                     Yb, Wqb, Wpb);
    gemm_qkv_mfma<<<dim3(1200), 256, 0, stream>>>(Yb, Wqb, qkv2);
    attn2_k<<<dim3(25, 8, NB), 256, 0, stream>>>(qkv2, X2);
    proj_mfma<<<dim3(800), 256, 0, stream>>>(X2, Wpb, b_proj, Yb, out);
}